// Round 15
// baseline (2191.448 us; speedup 1.0000x reference)
//
#include <hip/hip_runtime.h>

typedef unsigned short u16;
typedef unsigned int u32;
typedef unsigned long long u64;

#define NBLK 256

__device__ __forceinline__ float b2f(u16 u) {
    u32 i = ((u32)u) << 16;
    return __builtin_bit_cast(float, i);
}
__device__ __forceinline__ u16 f2b(float f) {
    u32 b = __builtin_bit_cast(u32, f);
    b += 0x7FFFu + ((b >> 16) & 1u);   // RNE
    return (u16)(b >> 16);
}
__device__ __forceinline__ float sigm(float x) {
    return 1.f / (1.f + __expf(-x));
}
__device__ __forceinline__ float tanh_fast(float x) {
    float a = fabsf(x);
    float e = __expf(-2.f * a);            // in (0,1], never inf
    float r = (1.f - e) / (1.f + e);
    return copysignf(r, x);
}

// ---------------------------------------------------------------------------
// Single persistent kernel. 256 WGs x 512 thr, 1 WG/CU.
//
// PROLOGUE (once, ~30-50us, all blocks parallel): block wg computes ITS OWN
//   Xp slice [t][wg*32..+32] for both encode phases into global Xp with
//   plain stores (same block reads them later -> same-XCD L2, coherent; no
//   atomics, no sentinel). Wih rows staged in LDS; register-light (wf[8] +
//   float4 temps), so kernel max-pressure is still set by the chain loop.
//
// CHAIN (round-8 champion, VERBATIM): Whh in fp32 registers w[4][32];
//   h exchange bf16-packed data-is-the-flag (poll hseqB[t-1] vs 0xFFFF);
//   xp double-buffered off the detect path; tail on wave 0; h store lanes
//   0-3 (16B coalesced).
// ---------------------------------------------------------------------------
__global__ void __launch_bounds__(512, 1)
rnn_coop(const float* __restrict__ WhhA, const float* __restrict__ WhhB,
         const float* __restrict__ pWih, const float* __restrict__ pWhh,
         const float* __restrict__ pB,
         const float* __restrict__ inWih, const float* __restrict__ outWih,
         const float* __restrict__ in_b, const float* __restrict__ out_b,
         const float* __restrict__ embed, const float* __restrict__ eos,
         const int* __restrict__ in_seq, const int* __restrict__ out_seq,
         float* __restrict__ Xp0, float* __restrict__ Xp1,
         u32* __restrict__ hseqB, float* __restrict__ out)
{
    __shared__ __align__(16) float wihS[32 * 512];   // 64KB (prologue only)
    __shared__ __align__(16) float xs[8][512];       // 16KB (prologue only)
    __shared__ __align__(16) float hs[2048];         // 8KB (chain)
    __shared__ float bs[32], gsum[32];

    const int wg = blockIdx.x;
    const int tid = threadIdx.x;
    const int lane = tid & 63;
    const int wv = tid >> 6;

    // ================= PROLOGUE: own Xp slice, both phases =================
    for (int p = 0; p < 2; ++p) {
        const float* __restrict__ Wih = p ? outWih : inWih;
        const float* __restrict__ bia = p ? out_b : in_b;
        const int*   __restrict__ sq  = p ? out_seq : in_seq;
        float* __restrict__ Xp = p ? Xp1 : Xp0;

        __syncthreads();                       // wihS/bs reuse safe (p=1)
        for (int idx = tid; idx < 4096; idx += 512) {     // 32 rows x 128 f4
            int s = idx >> 7, c4 = (idx & 127) << 2;      // s = gate*8+j
            size_t row = (size_t)((s >> 3) << 11) + (wg << 3) + (s & 7);
            *(float4*)&wihS[s * 512 + c4] = *(const float4*)&Wih[row * 512 + c4];
        }
        if (tid < 32)
            bs[tid] = bia[((tid >> 3) << 11) + (wg << 3) + (tid & 7)];
        __syncthreads();

        for (int grp = 0; grp < 33; ++grp) {
            const int t0 = grp * 8;
            const int nt = min(8, 257 - t0);
            for (int idx = tid; idx < nt * 512; idx += 512) {
                int tt = idx >> 9, col = idx & 511;
                int tk = t0 + tt;
                xs[tt][col] = (tk < 256) ? embed[(size_t)sq[tk] * 512 + col]
                                         : eos[col];
            }
            __syncthreads();

#pragma unroll 1
            for (int rr = 0; rr < 4; ++rr) {
                const int s = (wv << 2) + rr;
                float wf[8];
                *(float4*)&wf[0] = *(const float4*)&wihS[s * 512 + (lane << 2)];
                *(float4*)&wf[4] = *(const float4*)&wihS[s * 512 + 256 + (lane << 2)];
#pragma unroll
                for (int tt = 0; tt < 8; ++tt) {
                    float4 x0 = *(const float4*)&xs[tt][(lane << 2)];
                    float4 x1 = *(const float4*)&xs[tt][256 + (lane << 2)];
                    float a = 0.f;
                    a = fmaf(wf[0], x0.x, a); a = fmaf(wf[1], x0.y, a);
                    a = fmaf(wf[2], x0.z, a); a = fmaf(wf[3], x0.w, a);
                    a = fmaf(wf[4], x1.x, a); a = fmaf(wf[5], x1.y, a);
                    a = fmaf(wf[6], x1.z, a); a = fmaf(wf[7], x1.w, a);
#pragma unroll
                    for (int off = 32; off > 0; off >>= 1)
                        a += __shfl_xor(a, off, 64);
                    if (lane == 0 && tt < nt)
                        Xp[(size_t)(t0 + tt) * 8192 + (wg << 5) + s] = a + bs[s];
                }
            }
            __syncthreads();                   // protect xs before refill
        }
    }
    // ================= END PROLOGUE =================

    float w[4][32];        // fp32 Whh slice: rows rl=4*wv+rr, 32 cols/lane
    float c_reg = 0.f;     // valid on lanes 0-7 of wave 0

    if (tid < 32) gsum[tid] = 0.f;

    float xp_cur = 0.f, xp_nxt = 0.f;
    if (wv == 0 && lane < 32)
        xp_cur = Xp0[(wg << 5) + lane];        // t=0 (own store, L2-hit)

    for (int t = 0; t < 524; ++t) {
        const int phase = (t < 257) ? 0 : (t < 514) ? 1 : 2;

        if (t == 0 || t == 257 || t == 514) {
            if (phase < 2) {
                const float* Ws = phase ? WhhB : WhhA;
#pragma unroll
                for (int rr = 0; rr < 4; ++rr) {
                    int rl = (wv << 2) + rr;
                    const float* Wr = Ws + (size_t)(((rl >> 3) << 11) + (wg << 3) + (rl & 7)) * 2048;
#pragma unroll
                    for (int q = 0; q < 8; ++q)
                        *(float4*)&w[rr][q * 4] = *(const float4*)&Wr[(q << 8) + (lane << 2)];
                }
            } else {
#pragma unroll
                for (int rr = 0; rr < 4; ++rr) {
                    int rl = (wv << 2) + rr;
                    size_t off = (size_t)(((rl >> 3) << 11) + (wg << 3) + (rl & 7)) * 2048;
#pragma unroll
                    for (int q = 0; q < 8; ++q) {
                        float4 a = *(const float4*)&pWih[off + (q << 8) + (lane << 2)];
                        float4 b = *(const float4*)&pWhh[off + (q << 8) + (lane << 2)];
                        float4 s;
                        s.x = a.x + b.x; s.y = a.y + b.y;
                        s.z = a.z + b.z; s.w = a.w + b.w;
                        *(float4*)&w[rr][q * 4] = s;
                    }
                }
            }
        }

        if (t > 0) {
            // poll own u64 (4 bf16) of hseqB[t-1]; sentinel 0xFFFF per u16.
            // Producer writes u32 granules, so per-u16 checks are torn-safe.
            const u64* src = (const u64*)hseqB + (size_t)(t - 1) * 512 + tid;
            u64 a = __hip_atomic_load(src, __ATOMIC_RELAXED, __HIP_MEMORY_SCOPE_AGENT);
            while ((u16)a == 0xFFFFu || (u16)(a >> 16) == 0xFFFFu ||
                   (u16)(a >> 32) == 0xFFFFu || (u16)(a >> 48) == 0xFFFFu) {
                __builtin_amdgcn_s_sleep(1);
                a = __hip_atomic_load(src, __ATOMIC_RELAXED, __HIP_MEMORY_SCOPE_AGENT);
            }
            float4 hv;
            hv.x = b2f((u16)a);         hv.y = b2f((u16)(a >> 16));
            hv.z = b2f((u16)(a >> 32)); hv.w = b2f((u16)(a >> 48));
            *(float4*)&hs[tid << 2] = hv;       // 16B/lane, conflict-free
        }
        __syncthreads();

        // issue NEXT step's xp load here: covered by dot+reduce, and the
        // poll loop above never waits on it (nothing outstanding at poll)
        if (wv == 0 && lane < 32 && t < 523) {
            const int tn = t + 1;
            if (tn < 257)       xp_nxt = Xp0[(size_t)tn * 8192 + (wg << 5) + lane];
            else if (tn < 514)  xp_nxt = Xp1[(size_t)(tn - 257) * 8192 + (wg << 5) + lane];
            else                xp_nxt = pB[((lane >> 3) << 11) + (wg << 3) + (lane & 7)];
        }

        if (t > 0) {
            float a0 = 0.f, a1 = 0.f, a2 = 0.f, a3 = 0.f;
#pragma unroll
            for (int q = 0; q < 8; ++q) {
                float4 hv = *(const float4*)&hs[(q << 8) + (lane << 2)];
#pragma unroll
                for (int j = 0; j < 4; ++j) {
                    float h = ((const float*)&hv)[j];
                    a0 = fmaf(w[0][q * 4 + j], h, a0);
                    a1 = fmaf(w[1][q * 4 + j], h, a1);
                    a2 = fmaf(w[2][q * 4 + j], h, a2);
                    a3 = fmaf(w[3][q * 4 + j], h, a3);
                }
            }
#pragma unroll
            for (int off = 32; off > 0; off >>= 1) {
                a0 += __shfl_xor(a0, off, 64);
                a1 += __shfl_xor(a1, off, 64);
                a2 += __shfl_xor(a2, off, 64);
                a3 += __shfl_xor(a3, off, 64);
            }
            if (lane == 0) {
                const int rl = wv << 2;
                gsum[rl]     = a0;
                gsum[rl + 1] = a1;
                gsum[rl + 2] = a2;
                gsum[rl + 3] = a3;
            }
        }
        __syncthreads();

        if (wv == 0) {
            // 32 parallel activations (lanes 0-31); lanes >=32 compute garbage
            float tot = xp_cur + gsum[lane & 31];
            float act = ((lane >> 3) == 2) ? tanh_fast(tot) : sigm(tot);
            const int j = lane & 7;
            float fi = __shfl(act, j, 64);        // gate i
            float ff = __shfl(act, 8 + j, 64);    // gate f
            float fg = __shfl(act, 16 + j, 64);   // gate g~
            float fo = __shfl(act, 24 + j, 64);   // gate o
            c_reg = ff * c_reg + fi * fg;
            float h2 = fo * tanh_fast(c_reg);
            u32 hb = (u32)f2b(h2);
            u32 lo = (u32)__shfl((int)hb, (lane & 3) * 2, 64);
            u32 hi = (u32)__shfl((int)hb, (lane & 3) * 2 + 1, 64);
            if (lane < 4)
                __hip_atomic_store(&hseqB[(size_t)t * 1024 + (wg << 2) + lane],
                                   (hi << 16) | lo,
                                   __ATOMIC_RELAXED, __HIP_MEMORY_SCOPE_AGENT);
            if (phase == 2 && lane < 8)
                out[(size_t)(t - 514) * 2048 + (wg << 3) + lane] = h2;
        }
        xp_cur = xp_nxt;
        // no inter-block barrier: data arrival is the sync
    }
}

// ---------------------------------------------------------------------------
extern "C" void kernel_launch(void* const* d_in, const int* in_sizes, int n_in,
                              void* d_out, int out_size, void* d_ws, size_t ws_size,
                              hipStream_t stream) {
    const int*   in_seq   = (const int*)d_in[0];
    const int*   out_seq  = (const int*)d_in[1];
    const float* embed    = (const float*)d_in[2];
    const float* eos      = (const float*)d_in[3];
    const float* in_Wih   = (const float*)d_in[4];
    const float* in_Whh   = (const float*)d_in[5];
    const float* in_b     = (const float*)d_in[6];
    const float* out_Wih  = (const float*)d_in[7];
    const float* out_Whh  = (const float*)d_in[8];
    const float* out_b    = (const float*)d_in[9];
    const float* pg_Wih   = (const float*)d_in[10];
    const float* pg_Whh   = (const float*)d_in[11];
    const float* pg_b     = (const float*)d_in[12];

    float* Xp0   = (float*)d_ws;                       // 257*8192 fp32
    float* Xp1   = Xp0 + (size_t)257 * 8192;           // 257*8192 fp32
    u32*   hseqB = (u32*)(Xp1 + (size_t)257 * 8192);   // 524*1024 u32 (bf16 x2)

    // bf16 NaN sentinel 0xFFFF for the h exchange; fresh region per step
    hipMemsetAsync(hseqB, 0xFF, (size_t)524 * 1024 * sizeof(u32), stream);

    float* out = (float*)d_out;
    void* args[] = { (void*)&in_Whh, (void*)&out_Whh, (void*)&pg_Wih, (void*)&pg_Whh,
                     (void*)&pg_b,
                     (void*)&in_Wih, (void*)&out_Wih, (void*)&in_b, (void*)&out_b,
                     (void*)&embed, (void*)&eos, (void*)&in_seq, (void*)&out_seq,
                     (void*)&Xp0, (void*)&Xp1, (void*)&hseqB, (void*)&out };
    hipLaunchCooperativeKernel((const void*)rnn_coop, dim3(NBLK), dim3(512),
                               args, 0, stream);
}

// Round 16
// 1981.574 us; speedup vs baseline: 1.1059x; 1.1059x over previous
//
#include <hip/hip_runtime.h>

typedef unsigned short u16;
typedef unsigned int u32;
typedef unsigned long long u64;

#define NBLK 256

__device__ __forceinline__ float b2f(u16 u) {
    u32 i = ((u32)u) << 16;
    return __builtin_bit_cast(float, i);
}
__device__ __forceinline__ u16 f2b(float f) {
    u32 b = __builtin_bit_cast(u32, f);
    b += 0x7FFFu + ((b >> 16) & 1u);   // RNE
    return (u16)(b >> 16);
}
__device__ __forceinline__ float sigm(float x) {
    return 1.f / (1.f + __expf(-x));
}
__device__ __forceinline__ float tanh_fast(float x) {
    float a = fabsf(x);
    float e = __expf(-2.f * a);            // in (0,1], never inf
    float r = (1.f - e) / (1.f + e);
    return copysignf(r, x);
}

// ---------------------------------------------------------------------------
// Kernel A — W-STATIONARY xproj (round-14 version). grid (512), block 256
// (2 blocks/CU). Block bx: which = bx>>8 (in/out phase), slice = bx&255 ->
// 32 rows held in REGISTERS (w[8][8]/lane), x-rows staged 8-at-a-time in
// 16KB LDS, loop over all 33 t-groups. W read from HBM exactly once.
// Xp layout [t][wg][32], slot = wg*32 + g*8 + j for row r = g*2048+wg*8+j.
// ---------------------------------------------------------------------------
__global__ void __launch_bounds__(256)
xproj_kernel(const float* __restrict__ embed, const float* __restrict__ eos,
             const int* __restrict__ seqA, const int* __restrict__ seqB,
             const float* __restrict__ WA, const float* __restrict__ WB,
             const float* __restrict__ bA, const float* __restrict__ bB,
             float* __restrict__ XpA, float* __restrict__ XpB)
{
    __shared__ __align__(16) float xs[8][512];
    const int which = blockIdx.x >> 8;
    const int bx = blockIdx.x & 255;
    const int* __restrict__ seq  = which ? seqB : seqA;
    const float* __restrict__ W  = which ? WB : WA;
    const float* __restrict__ bias = which ? bB : bA;
    float* __restrict__ Xp = which ? XpB : XpA;

    const int tid = threadIdx.x;
    const int lane = tid & 63;
    const int wv = tid >> 6;

    // 8 rows per wave, held in registers for the whole kernel
    float w[8][8];
    float breg[8];
    int slot[8];
#pragma unroll
    for (int rr = 0; rr < 8; ++rr) {
        const int r = bx * 32 + wv * 8 + rr;
        *(float4*)&w[rr][0] = *(const float4*)&W[(size_t)r * 512 + (lane << 2)];
        *(float4*)&w[rr][4] = *(const float4*)&W[(size_t)r * 512 + 256 + (lane << 2)];
        breg[rr] = bias[r];
        int g = r >> 11, rem = r & 2047;
        slot[rr] = ((rem >> 3) << 5) + (g << 3) + (rem & 7);
    }

    for (int grp = 0; grp < 33; ++grp) {
        const int t0 = grp * 8;
        const int nt = min(8, 257 - t0);
        for (int idx = tid; idx < nt * 512; idx += 256) {
            int tt = idx >> 9, col = idx & 511;
            int t = t0 + tt;
            xs[tt][col] = (t < 256) ? embed[(size_t)seq[t] * 512 + col] : eos[col];
        }
        __syncthreads();

#pragma unroll 1
        for (int tt = 0; tt < 8; ++tt) {
            float xt[8];
            *(float4*)&xt[0] = *(const float4*)&xs[tt][(lane << 2)];
            *(float4*)&xt[4] = *(const float4*)&xs[tt][256 + (lane << 2)];
            float a[8];
#pragma unroll
            for (int rr = 0; rr < 8; ++rr) {
                float s = 0.f;
#pragma unroll
                for (int j = 0; j < 8; ++j) s = fmaf(w[rr][j], xt[j], s);
                a[rr] = s;
            }
#pragma unroll
            for (int off = 32; off > 0; off >>= 1) {
#pragma unroll
                for (int rr = 0; rr < 8; ++rr)
                    a[rr] += __shfl_xor(a[rr], off, 64);
            }
            if (lane == 0 && tt < nt) {
                float* dst = Xp + (size_t)(t0 + tt) * 8192;
#pragma unroll
                for (int rr = 0; rr < 8; ++rr)
                    dst[slot[rr]] = a[rr] + breg[rr];
            }
        }
        __syncthreads();   // protect xs before next overwrite
    }
}

// ---------------------------------------------------------------------------
// Kernel B: persistent LSTM (round-8/14 champion; only change: HOT poll --
// s_sleep removed, its backoff rationale was refuted by the r9 replication
// experiment and each sleep quantum sits on the serial chain).
// 256 WGs x 512 thr. Whh in fp32 registers w[4][32]; h exchange bf16-packed
// data-is-the-flag (poll hseqB[t-1] vs 0xFFFF sentinel); xp double-buffered
// off the detect path; tail on wave 0; h store lanes 0-3 (16B coalesced).
// ---------------------------------------------------------------------------
__global__ void __launch_bounds__(512, 1)
rnn_coop(const float* __restrict__ WhhA, const float* __restrict__ WhhB,
         const float* __restrict__ pWih, const float* __restrict__ pWhh,
         const float* __restrict__ pB,
         const float* __restrict__ Xp0, const float* __restrict__ Xp1,
         u32* __restrict__ hseqB, float* __restrict__ out)
{
    __shared__ __align__(16) float hs[2048];   // 8KB staged fp32 h
    __shared__ float gsum[32];

    const int wg = blockIdx.x;
    const int tid = threadIdx.x;
    const int lane = tid & 63;
    const int wv = tid >> 6;

    float w[4][32];        // fp32 weight slice: rows rl=4*wv+rr, 32 cols/lane
    float c_reg = 0.f;     // valid on lanes 0-7 of wave 0

    if (tid < 32) gsum[tid] = 0.f;

    float xp_cur = 0.f, xp_nxt = 0.f;
    if (wv == 0 && lane < 32)
        xp_cur = Xp0[(size_t)0 * 8192 + (wg << 5) + lane];   // t=0, phase 0

    for (int t = 0; t < 524; ++t) {
        const int phase = (t < 257) ? 0 : (t < 514) ? 1 : 2;

        if (t == 0 || t == 257 || t == 514) {
            if (phase < 2) {
                const float* Ws = phase ? WhhB : WhhA;
#pragma unroll
                for (int rr = 0; rr < 4; ++rr) {
                    int rl = (wv << 2) + rr;
                    const float* Wr = Ws + (size_t)(((rl >> 3) << 11) + (wg << 3) + (rl & 7)) * 2048;
#pragma unroll
                    for (int q = 0; q < 8; ++q)
                        *(float4*)&w[rr][q * 4] = *(const float4*)&Wr[(q << 8) + (lane << 2)];
                }
            } else {
#pragma unroll
                for (int rr = 0; rr < 4; ++rr) {
                    int rl = (wv << 2) + rr;
                    size_t off = (size_t)(((rl >> 3) << 11) + (wg << 3) + (rl & 7)) * 2048;
#pragma unroll
                    for (int q = 0; q < 8; ++q) {
                        float4 a = *(const float4*)&pWih[off + (q << 8) + (lane << 2)];
                        float4 b = *(const float4*)&pWhh[off + (q << 8) + (lane << 2)];
                        float4 s;
                        s.x = a.x + b.x; s.y = a.y + b.y;
                        s.z = a.z + b.z; s.w = a.w + b.w;
                        *(float4*)&w[rr][q * 4] = s;
                    }
                }
            }
        }

        if (t > 0) {
            // HOT poll of own u64 (4 bf16) of hseqB[t-1]; sentinel 0xFFFF
            // per u16. Producer writes u32 granules -> per-u16 checks are
            // torn-safe.
            const u64* src = (const u64*)hseqB + (size_t)(t - 1) * 512 + tid;
            u64 a = __hip_atomic_load(src, __ATOMIC_RELAXED, __HIP_MEMORY_SCOPE_AGENT);
            while ((u16)a == 0xFFFFu || (u16)(a >> 16) == 0xFFFFu ||
                   (u16)(a >> 32) == 0xFFFFu || (u16)(a >> 48) == 0xFFFFu)
                a = __hip_atomic_load(src, __ATOMIC_RELAXED, __HIP_MEMORY_SCOPE_AGENT);
            float4 hv;
            hv.x = b2f((u16)a);         hv.y = b2f((u16)(a >> 16));
            hv.z = b2f((u16)(a >> 32)); hv.w = b2f((u16)(a >> 48));
            *(float4*)&hs[tid << 2] = hv;       // 16B/lane, conflict-free
        }
        __syncthreads();

        // issue NEXT step's xp load here: covered by dot+reduce, and the
        // poll loop above never waits on it (nothing outstanding at poll)
        if (wv == 0 && lane < 32 && t < 523) {
            const int tn = t + 1;
            if (tn < 257)       xp_nxt = Xp0[(size_t)tn * 8192 + (wg << 5) + lane];
            else if (tn < 514)  xp_nxt = Xp1[(size_t)(tn - 257) * 8192 + (wg << 5) + lane];
            else                xp_nxt = pB[((lane >> 3) << 11) + (wg << 3) + (lane & 7)];
        }

        if (t > 0) {
            float a0 = 0.f, a1 = 0.f, a2 = 0.f, a3 = 0.f;
#pragma unroll
            for (int q = 0; q < 8; ++q) {
                float4 hv = *(const float4*)&hs[(q << 8) + (lane << 2)];
#pragma unroll
                for (int j = 0; j < 4; ++j) {
                    float h = ((const float*)&hv)[j];
                    a0 = fmaf(w[0][q * 4 + j], h, a0);
                    a1 = fmaf(w[1][q * 4 + j], h, a1);
                    a2 = fmaf(w[2][q * 4 + j], h, a2);
                    a3 = fmaf(w[3][q * 4 + j], h, a3);
                }
            }
#pragma unroll
            for (int off = 32; off > 0; off >>= 1) {
                a0 += __shfl_xor(a0, off, 64);
                a1 += __shfl_xor(a1, off, 64);
                a2 += __shfl_xor(a2, off, 64);
                a3 += __shfl_xor(a3, off, 64);
            }
            if (lane == 0) {
                const int rl = wv << 2;
                gsum[rl]     = a0;
                gsum[rl + 1] = a1;
                gsum[rl + 2] = a2;
                gsum[rl + 3] = a3;
            }
        }
        __syncthreads();

        if (wv == 0) {
            // 32 parallel activations (lanes 0-31); lanes >=32 compute garbage
            float tot = xp_cur + gsum[lane & 31];
            float act = ((lane >> 3) == 2) ? tanh_fast(tot) : sigm(tot);
            const int j = lane & 7;
            float fi = __shfl(act, j, 64);        // gate i
            float ff = __shfl(act, 8 + j, 64);    // gate f
            float fg = __shfl(act, 16 + j, 64);   // gate g~
            float fo = __shfl(act, 24 + j, 64);   // gate o
            c_reg = ff * c_reg + fi * fg;
            float h2 = fo * tanh_fast(c_reg);
            u32 hb = (u32)f2b(h2);
            u32 lo = (u32)__shfl((int)hb, (lane & 3) * 2, 64);
            u32 hi = (u32)__shfl((int)hb, (lane & 3) * 2 + 1, 64);
            if (lane < 4)
                __hip_atomic_store(&hseqB[(size_t)t * 1024 + (wg << 2) + lane],
                                   (hi << 16) | lo,
                                   __ATOMIC_RELAXED, __HIP_MEMORY_SCOPE_AGENT);
            if (phase == 2 && lane < 8)
                out[(size_t)(t - 514) * 2048 + (wg << 3) + lane] = h2;
        }
        xp_cur = xp_nxt;
        // no inter-block barrier: data arrival is the sync
    }
}

// ---------------------------------------------------------------------------
extern "C" void kernel_launch(void* const* d_in, const int* in_sizes, int n_in,
                              void* d_out, int out_size, void* d_ws, size_t ws_size,
                              hipStream_t stream) {
    const int*   in_seq   = (const int*)d_in[0];
    const int*   out_seq  = (const int*)d_in[1];
    const float* embed    = (const float*)d_in[2];
    const float* eos      = (const float*)d_in[3];
    const float* in_Wih   = (const float*)d_in[4];
    const float* in_Whh   = (const float*)d_in[5];
    const float* in_b     = (const float*)d_in[6];
    const float* out_Wih  = (const float*)d_in[7];
    const float* out_Whh  = (const float*)d_in[8];
    const float* out_b    = (const float*)d_in[9];
    const float* pg_Wih   = (const float*)d_in[10];
    const float* pg_Whh   = (const float*)d_in[11];
    const float* pg_b     = (const float*)d_in[12];

    float* Xp0   = (float*)d_ws;                       // 257*8192 fp32
    float* Xp1   = Xp0 + (size_t)257 * 8192;           // 257*8192 fp32
    u32*   hseqB = (u32*)(Xp1 + (size_t)257 * 8192);   // 524*1024 u32 (bf16 x2)

    // bf16 NaN sentinel 0xFFFF; fresh region per step -> no reuse races
    hipMemsetAsync(hseqB, 0xFF, (size_t)524 * 1024 * sizeof(u32), stream);

    hipLaunchKernelGGL(xproj_kernel, dim3(512), dim3(256), 0, stream,
                       embed, eos, in_seq, out_seq,
                       in_Wih, out_Wih, in_b, out_b, Xp0, Xp1);

    float* out = (float*)d_out;
    void* args[] = { (void*)&in_Whh, (void*)&out_Whh, (void*)&pg_Wih, (void*)&pg_Whh,
                     (void*)&pg_b, (void*)&Xp0, (void*)&Xp1, (void*)&hseqB, (void*)&out };
    hipLaunchCooperativeKernel((const void*)rnn_coop, dim3(NBLK), dim3(512),
                               args, 0, stream);
}

// Round 17
// 1908.316 us; speedup vs baseline: 1.1484x; 1.0384x over previous
//
#include <hip/hip_runtime.h>

typedef unsigned short u16;
typedef unsigned int u32;
typedef unsigned long long u64;

#define NBLK 256
#define XR 544   // swizzled xs row stride (words): col + ((col>>6)<<2) < 540

__device__ __forceinline__ float b2f(u16 u) {
    u32 i = ((u32)u) << 16;
    return __builtin_bit_cast(float, i);
}
__device__ __forceinline__ u16 f2b(float f) {
    u32 b = __builtin_bit_cast(u32, f);
    b += 0x7FFFu + ((b >> 16) & 1u);   // RNE
    return (u16)(b >> 16);
}
__device__ __forceinline__ float sigm(float x) {
    return 1.f / (1.f + __expf(-x));
}
__device__ __forceinline__ float tanh_fast(float x) {
    float a = fabsf(x);
    float e = __expf(-2.f * a);            // in (0,1], never inf
    float r = (1.f - e) / (1.f + e);
    return copysignf(r, x);
}

// ---------------------------------------------------------------------------
// Kernel A — xproj v3: 3-level reduction instead of 6-level tree.
// grid (512), block 256 (2 blocks/CU). Lane map: row = lane&7 (one gate-row
// per lane within the wave), seg = lane>>3 (64-element k-slice). Each lane
// holds its 64 w-elements in 16 float4 regs and produces ONE partial per tt;
// row-sum = 3 shfl_xor (8,16,32)  [was: 48 DS-routed shuffles per 8 rows].
// xs rows are pad-swizzled (col + ((col>>6)<<2)) so the seg*68-strided b128
// reads are bank-conflict-free (8-lane same-address broadcasts are free).
// Xp layout [t][wg][32], slot = wg*32 + g*8 + j for row r = g*2048+wg*8+j.
// ---------------------------------------------------------------------------
__global__ void __launch_bounds__(256)
xproj_kernel(const float* __restrict__ embed, const float* __restrict__ eos,
             const int* __restrict__ seqA, const int* __restrict__ seqB,
             const float* __restrict__ WA, const float* __restrict__ WB,
             const float* __restrict__ bA, const float* __restrict__ bB,
             float* __restrict__ XpA, float* __restrict__ XpB)
{
    __shared__ __align__(16) float xs[8 * XR];   // 17.4KB
    const int which = blockIdx.x >> 8;
    const int bx = blockIdx.x & 255;
    const int* __restrict__ seq  = which ? seqB : seqA;
    const float* __restrict__ W  = which ? WB : WA;
    const float* __restrict__ bias = which ? bB : bA;
    float* __restrict__ Xp = which ? XpB : XpA;

    const int tid = threadIdx.x;
    const int lane = tid & 63;
    const int wv = tid >> 6;
    const int row = lane & 7;     // gate-row within wave
    const int seg = lane >> 3;    // k-slice 0..7

    const int r = bx * 32 + wv * 8 + row;
    float4 w4[16];                // w[r][seg*64 .. +64] in registers
    {
        const float* wp = &W[(size_t)r * 512 + seg * 64];
#pragma unroll
        for (int c = 0; c < 16; ++c) w4[c] = *(const float4*)&wp[c * 4];
    }
    const float brow = bias[r];
    const int g = r >> 11, rem = r & 2047;
    const int slot = ((rem >> 3) << 5) + (g << 3) + (rem & 7);

    for (int grp = 0; grp < 33; ++grp) {
        const int t0 = grp * 8;
        const int nt = min(8, 257 - t0);
        __syncthreads();                       // xs reuse safe
        for (int idx = tid; idx < nt * 512; idx += 256) {
            int tt = idx >> 9, col = idx & 511;
            int tk = t0 + tt;
            float v = (tk < 256) ? embed[(size_t)seq[tk] * 512 + col] : eos[col];
            xs[tt * XR + col + ((col >> 6) << 2)] = v;    // swizzled store
        }
        __syncthreads();

#pragma unroll 1
        for (int tt = 0; tt < 8; ++tt) {
            const float* xrow = &xs[tt * XR + seg * 68];  // swizzled read base
            float a = 0.f;
#pragma unroll
            for (int c = 0; c < 16; ++c) {
                float4 xv = *(const float4*)&xrow[c * 4];
                a = fmaf(w4[c].x, xv.x, a);
                a = fmaf(w4[c].y, xv.y, a);
                a = fmaf(w4[c].z, xv.z, a);
                a = fmaf(w4[c].w, xv.w, a);
            }
            a += __shfl_xor(a, 8, 64);
            a += __shfl_xor(a, 16, 64);
            a += __shfl_xor(a, 32, 64);
            if (lane < 8 && tt < nt)
                Xp[(size_t)(t0 + tt) * 8192 + slot] = a + brow;
        }
    }
}

// ---------------------------------------------------------------------------
// Kernel B: persistent LSTM (round-16 champion, VERBATIM). 256 WGs x 512 thr.
// Whh in fp32 registers w[4][32]; h exchange bf16-packed data-is-the-flag
// (hot poll of hseqB[t-1] vs 0xFFFF sentinel); xp double-buffered off the
// detect path; tail on wave 0; h store lanes 0-3 (16B coalesced).
// ---------------------------------------------------------------------------
__global__ void __launch_bounds__(512, 1)
rnn_coop(const float* __restrict__ WhhA, const float* __restrict__ WhhB,
         const float* __restrict__ pWih, const float* __restrict__ pWhh,
         const float* __restrict__ pB,
         const float* __restrict__ Xp0, const float* __restrict__ Xp1,
         u32* __restrict__ hseqB, float* __restrict__ out)
{
    __shared__ __align__(16) float hs[2048];   // 8KB staged fp32 h
    __shared__ float gsum[32];

    const int wg = blockIdx.x;
    const int tid = threadIdx.x;
    const int lane = tid & 63;
    const int wv = tid >> 6;

    float w[4][32];        // fp32 weight slice: rows rl=4*wv+rr, 32 cols/lane
    float c_reg = 0.f;     // valid on lanes 0-7 of wave 0

    if (tid < 32) gsum[tid] = 0.f;

    float xp_cur = 0.f, xp_nxt = 0.f;
    if (wv == 0 && lane < 32)
        xp_cur = Xp0[(size_t)0 * 8192 + (wg << 5) + lane];   // t=0, phase 0

    for (int t = 0; t < 524; ++t) {
        const int phase = (t < 257) ? 0 : (t < 514) ? 1 : 2;

        if (t == 0 || t == 257 || t == 514) {
            if (phase < 2) {
                const float* Ws = phase ? WhhB : WhhA;
#pragma unroll
                for (int rr = 0; rr < 4; ++rr) {
                    int rl = (wv << 2) + rr;
                    const float* Wr = Ws + (size_t)(((rl >> 3) << 11) + (wg << 3) + (rl & 7)) * 2048;
#pragma unroll
                    for (int q = 0; q < 8; ++q)
                        *(float4*)&w[rr][q * 4] = *(const float4*)&Wr[(q << 8) + (lane << 2)];
                }
            } else {
#pragma unroll
                for (int rr = 0; rr < 4; ++rr) {
                    int rl = (wv << 2) + rr;
                    size_t off = (size_t)(((rl >> 3) << 11) + (wg << 3) + (rl & 7)) * 2048;
#pragma unroll
                    for (int q = 0; q < 8; ++q) {
                        float4 a = *(const float4*)&pWih[off + (q << 8) + (lane << 2)];
                        float4 b = *(const float4*)&pWhh[off + (q << 8) + (lane << 2)];
                        float4 s;
                        s.x = a.x + b.x; s.y = a.y + b.y;
                        s.z = a.z + b.z; s.w = a.w + b.w;
                        *(float4*)&w[rr][q * 4] = s;
                    }
                }
            }
        }

        if (t > 0) {
            // HOT poll of own u64 (4 bf16) of hseqB[t-1]; sentinel 0xFFFF
            // per u16. Producer writes u32 granules -> per-u16 checks are
            // torn-safe.
            const u64* src = (const u64*)hseqB + (size_t)(t - 1) * 512 + tid;
            u64 a = __hip_atomic_load(src, __ATOMIC_RELAXED, __HIP_MEMORY_SCOPE_AGENT);
            while ((u16)a == 0xFFFFu || (u16)(a >> 16) == 0xFFFFu ||
                   (u16)(a >> 32) == 0xFFFFu || (u16)(a >> 48) == 0xFFFFu)
                a = __hip_atomic_load(src, __ATOMIC_RELAXED, __HIP_MEMORY_SCOPE_AGENT);
            float4 hv;
            hv.x = b2f((u16)a);         hv.y = b2f((u16)(a >> 16));
            hv.z = b2f((u16)(a >> 32)); hv.w = b2f((u16)(a >> 48));
            *(float4*)&hs[tid << 2] = hv;       // 16B/lane, conflict-free
        }
        __syncthreads();

        // issue NEXT step's xp load here: covered by dot+reduce, and the
        // poll loop above never waits on it (nothing outstanding at poll)
        if (wv == 0 && lane < 32 && t < 523) {
            const int tn = t + 1;
            if (tn < 257)       xp_nxt = Xp0[(size_t)tn * 8192 + (wg << 5) + lane];
            else if (tn < 514)  xp_nxt = Xp1[(size_t)(tn - 257) * 8192 + (wg << 5) + lane];
            else                xp_nxt = pB[((lane >> 3) << 11) + (wg << 3) + (lane & 7)];
        }

        if (t > 0) {
            float a0 = 0.f, a1 = 0.f, a2 = 0.f, a3 = 0.f;
#pragma unroll
            for (int q = 0; q < 8; ++q) {
                float4 hv = *(const float4*)&hs[(q << 8) + (lane << 2)];
#pragma unroll
                for (int j = 0; j < 4; ++j) {
                    float h = ((const float*)&hv)[j];
                    a0 = fmaf(w[0][q * 4 + j], h, a0);
                    a1 = fmaf(w[1][q * 4 + j], h, a1);
                    a2 = fmaf(w[2][q * 4 + j], h, a2);
                    a3 = fmaf(w[3][q * 4 + j], h, a3);
                }
            }
#pragma unroll
            for (int off = 32; off > 0; off >>= 1) {
                a0 += __shfl_xor(a0, off, 64);
                a1 += __shfl_xor(a1, off, 64);
                a2 += __shfl_xor(a2, off, 64);
                a3 += __shfl_xor(a3, off, 64);
            }
            if (lane == 0) {
                const int rl = wv << 2;
                gsum[rl]     = a0;
                gsum[rl + 1] = a1;
                gsum[rl + 2] = a2;
                gsum[rl + 3] = a3;
            }
        }
        __syncthreads();

        if (wv == 0) {
            // 32 parallel activations (lanes 0-31); lanes >=32 compute garbage
            float tot = xp_cur + gsum[lane & 31];
            float act = ((lane >> 3) == 2) ? tanh_fast(tot) : sigm(tot);
            const int j = lane & 7;
            float fi = __shfl(act, j, 64);        // gate i
            float ff = __shfl(act, 8 + j, 64);    // gate f
            float fg = __shfl(act, 16 + j, 64);   // gate g~
            float fo = __shfl(act, 24 + j, 64);   // gate o
            c_reg = ff * c_reg + fi * fg;
            float h2 = fo * tanh_fast(c_reg);
            u32 hb = (u32)f2b(h2);
            u32 lo = (u32)__shfl((int)hb, (lane & 3) * 2, 64);
            u32 hi = (u32)__shfl((int)hb, (lane & 3) * 2 + 1, 64);
            if (lane < 4)
                __hip_atomic_store(&hseqB[(size_t)t * 1024 + (wg << 2) + lane],
                                   (hi << 16) | lo,
                                   __ATOMIC_RELAXED, __HIP_MEMORY_SCOPE_AGENT);
            if (phase == 2 && lane < 8)
                out[(size_t)(t - 514) * 2048 + (wg << 3) + lane] = h2;
        }
        xp_cur = xp_nxt;
        // no inter-block barrier: data arrival is the sync
    }
}

// ---------------------------------------------------------------------------
extern "C" void kernel_launch(void* const* d_in, const int* in_sizes, int n_in,
                              void* d_out, int out_size, void* d_ws, size_t ws_size,
                              hipStream_t stream) {
    const int*   in_seq   = (const int*)d_in[0];
    const int*   out_seq  = (const int*)d_in[1];
    const float* embed    = (const float*)d_in[2];
    const float* eos      = (const float*)d_in[3];
    const float* in_Wih   = (const float*)d_in[4];
    const float* in_Whh   = (const float*)d_in[5];
    const float* in_b     = (const float*)d_in[6];
    const float* out_Wih  = (const float*)d_in[7];
    const float* out_Whh  = (const float*)d_in[8];
    const float* out_b    = (const float*)d_in[9];
    const float* pg_Wih   = (const float*)d_in[10];
    const float* pg_Whh   = (const float*)d_in[11];
    const float* pg_b     = (const float*)d_in[12];

    float* Xp0   = (float*)d_ws;                       // 257*8192 fp32
    float* Xp1   = Xp0 + (size_t)257 * 8192;           // 257*8192 fp32
    u32*   hseqB = (u32*)(Xp1 + (size_t)257 * 8192);   // 524*1024 u32 (bf16 x2)

    // bf16 NaN sentinel 0xFFFF; fresh region per step -> no reuse races
    hipMemsetAsync(hseqB, 0xFF, (size_t)524 * 1024 * sizeof(u32), stream);

    hipLaunchKernelGGL(xproj_kernel, dim3(512), dim3(256), 0, stream,
                       embed, eos, in_seq, out_seq,
                       in_Wih, out_Wih, in_b, out_b, Xp0, Xp1);

    float* out = (float*)d_out;
    void* args[] = { (void*)&in_Whh, (void*)&out_Whh, (void*)&pg_Wih, (void*)&pg_Whh,
                     (void*)&pg_b, (void*)&Xp0, (void*)&Xp1, (void*)&hseqB, (void*)&out };
    hipLaunchCooperativeKernel((const void*)rnn_coop, dim3(NBLK), dim3(512),
                               args, 0, stream);
}

// Round 18
// 1810.709 us; speedup vs baseline: 1.2103x; 1.0539x over previous
//
#include <hip/hip_runtime.h>

typedef unsigned short u16;
typedef unsigned int u32;
typedef unsigned long long u64;

#define NBLK 256
#define XR 544   // swizzled xs row stride (words): col + ((col>>6)<<2) < 540

__device__ __forceinline__ float b2f(u16 u) {
    u32 i = ((u32)u) << 16;
    return __builtin_bit_cast(float, i);
}
__device__ __forceinline__ u16 f2b(float f) {
    u32 b = __builtin_bit_cast(u32, f);
    b += 0x7FFFu + ((b >> 16) & 1u);   // RNE
    return (u16)(b >> 16);
}
__device__ __forceinline__ float sigm(float x) {
    return 1.f / (1.f + __expf(-x));
}
__device__ __forceinline__ float tanh_fast(float x) {
    float a = fabsf(x);
    float e = __expf(-2.f * a);            // in (0,1], never inf
    float r = (1.f - e) / (1.f + e);
    return copysignf(r, x);
}

// ---------------------------------------------------------------------------
// Single persistent kernel. 256 WGs x 512 thr, 1 WG/CU.
//
// PROLOGUE (v3 structure, ~50-70us): block wg computes ITS OWN Xp slice
//   [514][32] into global with plain stores (same-block reads later -> same
//   L2; proven correct in r15). 8 waves = 4 gate-groups x 2 t-halves; each
//   lane holds one row's 64-element k-slice in 16 float4 regs; row-sum =
//   3 shfl_xor (the r17 win). Live set ~70 VGPR, dead before the chain.
//
// CHAIN (r16 champion, VERBATIM): Whh in fp32 registers w[4][32]; h exchange
//   bf16-packed data-is-the-flag (hot poll vs 0xFFFF); xp double-buffered
//   off the detect path; tail on wave 0; h store lanes 0-3 (16B coalesced).
// ---------------------------------------------------------------------------
__global__ void __launch_bounds__(512, 1)
rnn_coop(const float* __restrict__ WhhA, const float* __restrict__ WhhB,
         const float* __restrict__ pWih, const float* __restrict__ pWhh,
         const float* __restrict__ pB,
         const float* __restrict__ inWih, const float* __restrict__ outWih,
         const float* __restrict__ in_b, const float* __restrict__ out_b,
         const float* __restrict__ embed, const float* __restrict__ eos,
         const int* __restrict__ in_seq, const int* __restrict__ out_seq,
         float* __restrict__ Xp0, float* __restrict__ Xp1,
         u32* __restrict__ hseqB, float* __restrict__ out)
{
    __shared__ __align__(16) float xs[8 * XR];   // 17.4KB (prologue)
    __shared__ __align__(16) float hs[2048];     // 8KB (chain)
    __shared__ float gsum[32];

    const int wg = blockIdx.x;
    const int tid = threadIdx.x;
    const int lane = tid & 63;
    const int wv = tid >> 6;

    // ================= PROLOGUE: own Xp slice, v3 layout =================
    {
        const int g = wv & 3;        // gate group (4 waves cover g=0..3)
        const int th = wv >> 2;      // t-half: waves 0-3 tt 0-3, waves 4-7 tt 4-7
        const int j = lane & 7;      // row within gate group
        const int seg = lane >> 3;   // 64-element k-slice
        const int r = (g << 11) + (wg << 3) + j;
        const int slot = (wg << 5) + (g << 3) + j;

        for (int p = 0; p < 2; ++p) {
            const float* __restrict__ Wih = p ? outWih : inWih;
            const float* __restrict__ bia = p ? out_b : in_b;
            const int*   __restrict__ sq  = p ? out_seq : in_seq;
            float* __restrict__ Xp = p ? Xp1 : Xp0;

            float4 w4[16];           // row r, cols seg*64..+64
            {
                const float* wp = &Wih[(size_t)r * 512 + seg * 64];
#pragma unroll
                for (int c = 0; c < 16; ++c) w4[c] = *(const float4*)&wp[c * 4];
            }
            const float brow = bia[r];

            for (int grp = 0; grp < 33; ++grp) {
                const int t0 = grp * 8;
                const int nt = min(8, 257 - t0);
                __syncthreads();                   // xs reuse safe
                for (int idx = tid; idx < nt * 512; idx += 512) {
                    int tt = idx >> 9, col = idx & 511;
                    int tk = t0 + tt;
                    float v = (tk < 256) ? embed[(size_t)sq[tk] * 512 + col]
                                         : eos[col];
                    xs[tt * XR + col + ((col >> 6) << 2)] = v;   // swizzled
                }
                __syncthreads();

#pragma unroll
                for (int q4 = 0; q4 < 4; ++q4) {
                    const int tt = th * 4 + q4;
                    if (tt < nt) {
                        const float* xrow = &xs[tt * XR + seg * 68];
                        float a = 0.f;
#pragma unroll
                        for (int c = 0; c < 16; ++c) {
                            float4 xv = *(const float4*)&xrow[c * 4];
                            a = fmaf(w4[c].x, xv.x, a);
                            a = fmaf(w4[c].y, xv.y, a);
                            a = fmaf(w4[c].z, xv.z, a);
                            a = fmaf(w4[c].w, xv.w, a);
                        }
                        a += __shfl_xor(a, 8, 64);
                        a += __shfl_xor(a, 16, 64);
                        a += __shfl_xor(a, 32, 64);
                        if (lane < 8)
                            Xp[(size_t)(t0 + tt) * 8192 + slot] = a + brow;
                    }
                }
            }
        }
        __syncthreads();
    }
    // ================= END PROLOGUE =================

    float w[4][32];        // fp32 Whh slice: rows rl=4*wv+rr, 32 cols/lane
    float c_reg = 0.f;     // valid on lanes 0-7 of wave 0

    if (tid < 32) gsum[tid] = 0.f;

    float xp_cur = 0.f, xp_nxt = 0.f;
    if (wv == 0 && lane < 32)
        xp_cur = Xp0[(wg << 5) + lane];        // t=0 (own store, L2-hit)

    for (int t = 0; t < 524; ++t) {
        const int phase = (t < 257) ? 0 : (t < 514) ? 1 : 2;

        if (t == 0 || t == 257 || t == 514) {
            if (phase < 2) {
                const float* Ws = phase ? WhhB : WhhA;
#pragma unroll
                for (int rr = 0; rr < 4; ++rr) {
                    int rl = (wv << 2) + rr;
                    const float* Wr = Ws + (size_t)(((rl >> 3) << 11) + (wg << 3) + (rl & 7)) * 2048;
#pragma unroll
                    for (int q = 0; q < 8; ++q)
                        *(float4*)&w[rr][q * 4] = *(const float4*)&Wr[(q << 8) + (lane << 2)];
                }
            } else {
#pragma unroll
                for (int rr = 0; rr < 4; ++rr) {
                    int rl = (wv << 2) + rr;
                    size_t off = (size_t)(((rl >> 3) << 11) + (wg << 3) + (rl & 7)) * 2048;
#pragma unroll
                    for (int q = 0; q < 8; ++q) {
                        float4 a = *(const float4*)&pWih[off + (q << 8) + (lane << 2)];
                        float4 b = *(const float4*)&pWhh[off + (q << 8) + (lane << 2)];
                        float4 s;
                        s.x = a.x + b.x; s.y = a.y + b.y;
                        s.z = a.z + b.z; s.w = a.w + b.w;
                        *(float4*)&w[rr][q * 4] = s;
                    }
                }
            }
        }

        if (t > 0) {
            // HOT poll of own u64 (4 bf16) of hseqB[t-1]; sentinel 0xFFFF
            // per u16. Producer writes u32 granules -> per-u16 checks are
            // torn-safe.
            const u64* src = (const u64*)hseqB + (size_t)(t - 1) * 512 + tid;
            u64 a = __hip_atomic_load(src, __ATOMIC_RELAXED, __HIP_MEMORY_SCOPE_AGENT);
            while ((u16)a == 0xFFFFu || (u16)(a >> 16) == 0xFFFFu ||
                   (u16)(a >> 32) == 0xFFFFu || (u16)(a >> 48) == 0xFFFFu)
                a = __hip_atomic_load(src, __ATOMIC_RELAXED, __HIP_MEMORY_SCOPE_AGENT);
            float4 hv;
            hv.x = b2f((u16)a);         hv.y = b2f((u16)(a >> 16));
            hv.z = b2f((u16)(a >> 32)); hv.w = b2f((u16)(a >> 48));
            *(float4*)&hs[tid << 2] = hv;       // 16B/lane, conflict-free
        }
        __syncthreads();

        // issue NEXT step's xp load here: covered by dot+reduce, and the
        // poll loop above never waits on it (nothing outstanding at poll)
        if (wv == 0 && lane < 32 && t < 523) {
            const int tn = t + 1;
            if (tn < 257)       xp_nxt = Xp0[(size_t)tn * 8192 + (wg << 5) + lane];
            else if (tn < 514)  xp_nxt = Xp1[(size_t)(tn - 257) * 8192 + (wg << 5) + lane];
            else                xp_nxt = pB[((lane >> 3) << 11) + (wg << 3) + (lane & 7)];
        }

        if (t > 0) {
            float a0 = 0.f, a1 = 0.f, a2 = 0.f, a3 = 0.f;
#pragma unroll
            for (int q = 0; q < 8; ++q) {
                float4 hv = *(const float4*)&hs[(q << 8) + (lane << 2)];
#pragma unroll
                for (int j = 0; j < 4; ++j) {
                    float h = ((const float*)&hv)[j];
                    a0 = fmaf(w[0][q * 4 + j], h, a0);
                    a1 = fmaf(w[1][q * 4 + j], h, a1);
                    a2 = fmaf(w[2][q * 4 + j], h, a2);
                    a3 = fmaf(w[3][q * 4 + j], h, a3);
                }
            }
#pragma unroll
            for (int off = 32; off > 0; off >>= 1) {
                a0 += __shfl_xor(a0, off, 64);
                a1 += __shfl_xor(a1, off, 64);
                a2 += __shfl_xor(a2, off, 64);
                a3 += __shfl_xor(a3, off, 64);
            }
            if (lane == 0) {
                const int rl = wv << 2;
                gsum[rl]     = a0;
                gsum[rl + 1] = a1;
                gsum[rl + 2] = a2;
                gsum[rl + 3] = a3;
            }
        }
        __syncthreads();

        if (wv == 0) {
            // 32 parallel activations (lanes 0-31); lanes >=32 compute garbage
            float tot = xp_cur + gsum[lane & 31];
            float act = ((lane >> 3) == 2) ? tanh_fast(tot) : sigm(tot);
            const int j = lane & 7;
            float fi = __shfl(act, j, 64);        // gate i
            float ff = __shfl(act, 8 + j, 64);    // gate f
            float fg = __shfl(act, 16 + j, 64);   // gate g~
            float fo = __shfl(act, 24 + j, 64);   // gate o
            c_reg = ff * c_reg + fi * fg;
            float h2 = fo * tanh_fast(c_reg);
            u32 hb = (u32)f2b(h2);
            u32 lo = (u32)__shfl((int)hb, (lane & 3) * 2, 64);
            u32 hi = (u32)__shfl((int)hb, (lane & 3) * 2 + 1, 64);
            if (lane < 4)
                __hip_atomic_store(&hseqB[(size_t)t * 1024 + (wg << 2) + lane],
                                   (hi << 16) | lo,
                                   __ATOMIC_RELAXED, __HIP_MEMORY_SCOPE_AGENT);
            if (phase == 2 && lane < 8)
                out[(size_t)(t - 514) * 2048 + (wg << 3) + lane] = h2;
        }
        xp_cur = xp_nxt;
        // no inter-block barrier: data arrival is the sync
    }
}

// ---------------------------------------------------------------------------
extern "C" void kernel_launch(void* const* d_in, const int* in_sizes, int n_in,
                              void* d_out, int out_size, void* d_ws, size_t ws_size,
                              hipStream_t stream) {
    const int*   in_seq   = (const int*)d_in[0];
    const int*   out_seq  = (const int*)d_in[1];
    const float* embed    = (const float*)d_in[2];
    const float* eos      = (const float*)d_in[3];
    const float* in_Wih   = (const float*)d_in[4];
    const float* in_Whh   = (const float*)d_in[5];
    const float* in_b     = (const float*)d_in[6];
    const float* out_Wih  = (const float*)d_in[7];
    const float* out_Whh  = (const float*)d_in[8];
    const float* out_b    = (const float*)d_in[9];
    const float* pg_Wih   = (const float*)d_in[10];
    const float* pg_Whh   = (const float*)d_in[11];
    const float* pg_b     = (const float*)d_in[12];

    float* Xp0   = (float*)d_ws;                       // 257*8192 fp32
    float* Xp1   = Xp0 + (size_t)257 * 8192;           // 257*8192 fp32
    u32*   hseqB = (u32*)(Xp1 + (size_t)257 * 8192);   // 524*1024 u32 (bf16 x2)

    // bf16 NaN sentinel 0xFFFF for the h exchange; fresh region per step
    hipMemsetAsync(hseqB, 0xFF, (size_t)524 * 1024 * sizeof(u32), stream);

    float* out = (float*)d_out;
    void* args[] = { (void*)&in_Whh, (void*)&out_Whh, (void*)&pg_Wih, (void*)&pg_Whh,
                     (void*)&pg_b,
                     (void*)&in_Wih, (void*)&out_Wih, (void*)&in_b, (void*)&out_b,
                     (void*)&embed, (void*)&eos, (void*)&in_seq, (void*)&out_seq,
                     (void*)&Xp0, (void*)&Xp1, (void*)&hseqB, (void*)&out };
    hipLaunchCooperativeKernel((const void*)rnn_coop, dim3(NBLK), dim3(512),
                               args, 0, stream);
}